// Round 3
// baseline (277.333 us; speedup 1.0000x reference)
//
#include <hip/hip_runtime.h>

#define B_   128
#define L_   196
#define ENC_ 2048
#define DEC_ 512
#define ATT_ 512
#define M_   (B_ * L_)   // 25088

typedef _Float16 f16x4 __attribute__((ext_vector_type(4)));
typedef _Float16 f16x8 __attribute__((ext_vector_type(8)));
typedef __fp16   h16x2 __attribute__((ext_vector_type(2)));
typedef float    f32x4 __attribute__((ext_vector_type(4)));

// ---------------- ws layout ----------------
// [0,          262144)   dec_map  f32 [128][512]
// [262144,    2359296)   WeT      f16 [512][2048]   (N-major, K contiguous)
// [2359296,   2760704)   partial  f32 [4][25088]    (per-N-tile partial scores)

// We [2048][512] fp32 -> WeT [512][2048] f16 (transposed)
__global__ void wet_kernel(const float* __restrict__ We, _Float16* __restrict__ WeT) {
    int idx = blockIdx.x * 256 + threadIdx.x;      // over 512*2048 = 1M
    int n = idx >> 11;
    int k = idx & 2047;
    WeT[idx] = (_Float16)We[k * ATT_ + n];
}

// dec_map[b][a] = decoder_hidden[b] . Wd[:,a] + bd[a]
__global__ void decmap_kernel(const float* __restrict__ dh, const float* __restrict__ Wd,
                              const float* __restrict__ bd, float* __restrict__ dec) {
    int b = blockIdx.x;       // 128
    int a = threadIdx.x;      // 512
    float acc = bd[a];
    const float* dhp = dh + b * DEC_;
#pragma unroll 8
    for (int k = 0; k < DEC_; ++k) acc += dhp[k] * Wd[k * ATT_ + a];
    dec[b * ATT_ + a] = acc;
}

// Main fused GEMM: 128(M) x 128(N) tile, K=2048, f16 MFMA, double-buffered LDS,
// async reg-staged A (fp32->f16 convert) and B, one barrier per K-step.
// LDS layout: unpadded [128][64] f16 per operand, XOR-swizzled in 16B units:
//   unit(row,k8) = row*8 + (k8 ^ (row&7))   (k8 = K/8 index, 0..7)
// -> ds_write_b128 full-bank coverage, ds_read_b128 2-way (free).
__global__ __launch_bounds__(256, 2)
void gemm_score_kernel(const float* __restrict__ enc,
                       const _Float16* __restrict__ WeT,
                       const float* __restrict__ be,
                       const float* __restrict__ wa,
                       const float* __restrict__ dec,
                       float* __restrict__ partial) {
    __shared__ _Float16 smem[2][2][128 * 64];   // [buf][A=0/B=1][unit*8]
    __shared__ float red[2][128];

    // XCD-chunked swizzle: keep the 4 ntile-siblings of one mtile on one XCD.
    int bid = blockIdx.x;
    int sid = (bid & 7) * 98 + (bid >> 3);           // bijective on [0,784)
    int mtile = sid >> 2;                            // 0..195
    int ntile = sid & 3;                             // 0..3

    int tid  = threadIdx.x;
    int lane = tid & 63, wid = tid >> 6;
    int wm = wid >> 1, wn = wid & 1;                 // 2x2 waves of 64x64
    int l15 = lane & 15, lg = lane >> 4;

    // staging map: thread covers row = tid&127, k8 in [k8b, k8b+4)
    int srow = tid & 127;
    int k8b  = (tid >> 7) * 4;                       // 0 or 4

    const float*    ag = enc + (size_t)(mtile * 128 + srow) * ENC_ + k8b * 8;
    const _Float16* bg = WeT + (size_t)(ntile * 128 + srow) * ENC_ + k8b * 8;

    int wunit[4];
#pragma unroll
    for (int u = 0; u < 4; ++u)
        wunit[u] = srow * 8 + ((k8b + u) ^ (srow & 7));

    // fragment read bases (swizzled): row_a = wm*64+mi*16+l15, row_b = wn*64+ni*16+l15
    int xorv = l15 & 7;                              // (row&7) for all frag rows
    int arow[4], brow[4];
#pragma unroll
    for (int i = 0; i < 4; ++i) {
        arow[i] = (wm * 64 + i * 16 + l15) * 8;
        brow[i] = (wn * 64 + i * 16 + l15) * 8;
    }

    float4 areg[8];
    f16x8  breg[4];

    f32x4 acc[4][4];
#pragma unroll
    for (int mi = 0; mi < 4; ++mi)
#pragma unroll
        for (int ni = 0; ni < 4; ++ni) acc[mi][ni] = (f32x4){0.f, 0.f, 0.f, 0.f};

    auto load_tile = [&](int kt) {
        const float*    a = ag + kt * 64;
        const _Float16* b = bg + kt * 64;
#pragma unroll
        for (int u = 0; u < 4; ++u) {
            areg[2 * u]     = *reinterpret_cast<const float4*>(a + u * 8);
            areg[2 * u + 1] = *reinterpret_cast<const float4*>(a + u * 8 + 4);
            breg[u]         = *reinterpret_cast<const f16x8*>(b + u * 8);
        }
    };
    auto write_tile = [&](int buf) {
        _Float16* As = smem[buf][0];
        _Float16* Bs = smem[buf][1];
#pragma unroll
        for (int u = 0; u < 4; ++u) {
            union { h16x2 h2[4]; f16x8 h8; } cv;
            cv.h2[0] = __builtin_amdgcn_cvt_pkrtz(areg[2 * u].x, areg[2 * u].y);
            cv.h2[1] = __builtin_amdgcn_cvt_pkrtz(areg[2 * u].z, areg[2 * u].w);
            cv.h2[2] = __builtin_amdgcn_cvt_pkrtz(areg[2 * u + 1].x, areg[2 * u + 1].y);
            cv.h2[3] = __builtin_amdgcn_cvt_pkrtz(areg[2 * u + 1].z, areg[2 * u + 1].w);
            *reinterpret_cast<f16x8*>(As + wunit[u] * 8) = cv.h8;
            *reinterpret_cast<f16x8*>(Bs + wunit[u] * 8) = breg[u];
        }
    };

    // prologue: stage tile 0
    load_tile(0);
    write_tile(0);
    __syncthreads();

    int cur = 0;
    for (int kt = 0; kt < ENC_ / 64; ++kt) {
        if (kt < ENC_ / 64 - 1) load_tile(kt + 1);   // issue early (T14)
        const _Float16* As = smem[cur][0];
        const _Float16* Bs = smem[cur][1];
#pragma unroll
        for (int ks = 0; ks < 2; ++ks) {
            int kx = (ks * 4 + lg) ^ xorv;
            f16x8 af[4], bf[4];
#pragma unroll
            for (int mi = 0; mi < 4; ++mi)
                af[mi] = *reinterpret_cast<const f16x8*>(As + (arow[mi] + kx) * 8);
#pragma unroll
            for (int ni = 0; ni < 4; ++ni)
                bf[ni] = *reinterpret_cast<const f16x8*>(Bs + (brow[ni] + kx) * 8);
#pragma unroll
            for (int mi = 0; mi < 4; ++mi)
#pragma unroll
                for (int ni = 0; ni < 4; ++ni)
                    acc[mi][ni] = __builtin_amdgcn_mfma_f32_16x16x32_f16(
                        af[mi], bf[ni], acc[mi][ni], 0, 0, 0);
        }
        if (kt < ENC_ / 64 - 1) write_tile(cur ^ 1); // waits vmcnt on issued loads
        __syncthreads();                             // one barrier per K-step
        cur ^= 1;
    }

    // Epilogue: x = acc + be[n] + dec[b][n]; t = tanh(x); rowsum += t*wa[n]
    float rsum[4][4];
#pragma unroll
    for (int mi = 0; mi < 4; ++mi)
#pragma unroll
        for (int j = 0; j < 4; ++j) rsum[mi][j] = 0.f;

    int nb = ntile * 128 + wn * 64;
    int rb = mtile * 128 + wm * 64;
#pragma unroll
    for (int ni = 0; ni < 4; ++ni) {
        int n = nb + ni * 16 + l15;
        float wav = wa[n];
        float bev = be[n];
#pragma unroll
        for (int mi = 0; mi < 4; ++mi) {
#pragma unroll
            for (int j = 0; j < 4; ++j) {
                int row = rb + mi * 16 + lg * 4 + j;    // C/D: col=lane&15, row=(lane>>4)*4+reg
                int b = row / L_;
                float x = acc[mi][ni][j] + bev + dec[b * ATT_ + n];
                float e = __expf(2.0f * x);
                float t = 1.0f - 2.0f / (e + 1.0f);     // tanh(x), inf-safe
                rsum[mi][j] += t * wav;
            }
        }
    }
    // reduce over the 16 lanes holding the same rows (l15 = n-direction)
#pragma unroll
    for (int mi = 0; mi < 4; ++mi) {
#pragma unroll
        for (int j = 0; j < 4; ++j) {
            float v = rsum[mi][j];
            v += __shfl_xor(v, 1);
            v += __shfl_xor(v, 2);
            v += __shfl_xor(v, 4);
            v += __shfl_xor(v, 8);
            if (l15 == 0) red[wn][wm * 64 + mi * 16 + lg * 4 + j] = v;
        }
    }
    __syncthreads();
    if (tid < 128)
        partial[(size_t)ntile * M_ + mtile * 128 + tid] = red[0][tid] + red[1][tid];
}

// softmax over L per batch row. ba cancels in softmax -> skipped.
__global__ void softmax_kernel(const float* __restrict__ partial, float* __restrict__ alphas) {
    int b = blockIdx.x, t = threadIdx.x;     // 128 blocks x 256 threads
    int lane = t & 63, wid = t >> 6;
    __shared__ float red[4];
    float s = 0.f, val = -1e30f;
    if (t < L_) {
        int r = b * L_ + t;
        s = partial[r] + partial[M_ + r] + partial[2 * M_ + r] + partial[3 * M_ + r];
        val = s;
    }
    float m = val;
#pragma unroll
    for (int off = 1; off < 64; off <<= 1) m = fmaxf(m, __shfl_xor(m, off));
    if (lane == 0) red[wid] = m;
    __syncthreads();
    m = fmaxf(fmaxf(red[0], red[1]), fmaxf(red[2], red[3]));
    float e = (t < L_) ? __expf(s - m) : 0.f;
    float sum = e;
#pragma unroll
    for (int off = 1; off < 64; off <<= 1) sum += __shfl_xor(sum, off);
    __syncthreads();
    if (lane == 0) red[wid] = sum;
    __syncthreads();
    sum = red[0] + red[1] + red[2] + red[3];
    if (t < L_) alphas[b * L_ + t] = e / sum;
}

// context[b][e] = sum_l alphas[b][l] * enc[b][l][e]   (memory-bound pass)
__global__ void context_kernel(const float* __restrict__ enc, const float* __restrict__ alphas,
                               float* __restrict__ ctx) {
    int b = blockIdx.x >> 2;                  // 128 b x 4 e-chunks = 512 blocks
    int ec = blockIdx.x & 3;
    int e = ec * 512 + threadIdx.x * 2;
    const float* ep = enc + (size_t)b * L_ * ENC_ + e;
    const float* ap = alphas + b * L_;
    float ax = 0.f, ay = 0.f;
#pragma unroll 4
    for (int l = 0; l < L_; ++l) {
        float a = ap[l];
        float2 v = *reinterpret_cast<const float2*>(ep + (size_t)l * ENC_);
        ax += a * v.x;
        ay += a * v.y;
    }
    float2 r; r.x = ax; r.y = ay;
    *reinterpret_cast<float2*>(&ctx[b * ENC_ + e]) = r;
}

extern "C" void kernel_launch(void* const* d_in, const int* in_sizes, int n_in,
                              void* d_out, int out_size, void* d_ws, size_t ws_size,
                              hipStream_t stream) {
    const float* enc = (const float*)d_in[0];
    const float* dh  = (const float*)d_in[1];
    const float* We  = (const float*)d_in[2];
    const float* be  = (const float*)d_in[3];
    const float* Wd  = (const float*)d_in[4];
    const float* bd  = (const float*)d_in[5];
    const float* wa  = (const float*)d_in[6];
    // d_in[7] = ba: shifts all scores equally -> cancels in softmax, unused.

    float* out    = (float*)d_out;
    float* ctx    = out;               // [128][2048]
    float* alphas = out + B_ * ENC_;   // [128][196]

    char* ws = (char*)d_ws;
    float*    dec     = (float*)ws;                            // 256 KiB
    _Float16* WeT     = (_Float16*)(ws + 262144);              // 2 MiB
    float*    partial = (float*)(ws + 262144 + 2097152);       // 392 KiB

    hipLaunchKernelGGL(wet_kernel,        dim3(4096), dim3(256), 0, stream, We, WeT);
    hipLaunchKernelGGL(decmap_kernel,     dim3(128),  dim3(512), 0, stream, dh, Wd, bd, dec);
    hipLaunchKernelGGL(gemm_score_kernel, dim3(784),  dim3(256), 0, stream, enc, WeT, be, wa, dec, partial);
    hipLaunchKernelGGL(softmax_kernel,    dim3(128),  dim3(256), 0, stream, partial, alphas);
    hipLaunchKernelGGL(context_kernel,    dim3(512),  dim3(256), 0, stream, enc, alphas, ctx);
}

// Round 4
// 157.547 us; speedup vs baseline: 1.7603x; 1.7603x over previous
//
#include <hip/hip_runtime.h>

#define B_   128
#define L_   196
#define ENC_ 2048
#define DEC_ 512
#define ATT_ 512
#define M_   (B_ * L_)   // 25088

typedef _Float16 f16x4 __attribute__((ext_vector_type(4)));
typedef _Float16 f16x8 __attribute__((ext_vector_type(8)));
typedef __fp16   h16x2 __attribute__((ext_vector_type(2)));
typedef float    f32x4 __attribute__((ext_vector_type(4)));

// ---------------- ws layout ----------------
// [0,          262144)   dec_map  f32 [128][512]
// [262144,    2359296)   WeTs     f16 tiled: [ntile=4][kt=64][k8=4][row=128] x f16x8 unit
// [2359296,   2760704)   partial  f32 [4][25088]

// We [2048][512] fp32 -> WeTs tiled-f16. Unit (nt,kt,k8,row) holds
// We[kt*32+k8*8+j][nt*128+row] for j=0..7.
__global__ void wets_kernel(const float* __restrict__ We, _Float16* __restrict__ WeTs) {
    int u = blockIdx.x * 256 + threadIdx.x;     // 131072 units
    int row = u & 127;
    int k8  = (u >> 7) & 3;
    int kt  = (u >> 9) & 63;
    int nt  = u >> 15;
    int n  = nt * 128 + row;
    int k0 = kt * 32 + k8 * 8;
    f16x8 h;
#pragma unroll
    for (int j = 0; j < 8; ++j) h[j] = (_Float16)We[(k0 + j) * ATT_ + n];
    *reinterpret_cast<f16x8*>(WeTs + (size_t)u * 8) = h;
}

// dec_map[b][a] = decoder_hidden[b] . Wd[:,a] + bd[a]
__global__ void decmap_kernel(const float* __restrict__ dh, const float* __restrict__ Wd,
                              const float* __restrict__ bd, float* __restrict__ dec) {
    int b = blockIdx.x;       // 128
    int a = threadIdx.x;      // 512
    float acc = bd[a];
    const float* dhp = dh + b * DEC_;
#pragma unroll 8
    for (int k = 0; k < DEC_; ++k) acc += dhp[k] * Wd[k * ATT_ + a];
    dec[b * ATT_ + a] = acc;
}

// Fused GEMM: 128x128 tile, BK=32, double-buffered LDS, transposed-unit layout
// LDS[op]: [k8=4][row=128] 16B units (8KB per operand per buffer).
// Frag reads / A writes / B writes are all disjoint-contiguous chunks -> conflict-free.
// Coalesced global staging: A row-major 4 lanes x 32B per row; B pre-tiled linear.
__global__ __launch_bounds__(256, 4)
void gemm_score_kernel(const float* __restrict__ enc,
                       const _Float16* __restrict__ WeTs,
                       const float* __restrict__ be,
                       const float* __restrict__ wa,
                       const float* __restrict__ dec,
                       float* __restrict__ partial) {
    __shared__ _Float16 smem[2][2][4096];   // [buf][A=0/B=1][(k8*128+row)*8]
    __shared__ float red[2][128];

    // XCD-chunked swizzle: 4 ntile-siblings of one mtile stay on one XCD.
    int bid = blockIdx.x;
    int sid = (bid & 7) * 98 + (bid >> 3);           // bijective on [0,784)
    int mtile = sid >> 2;                            // 0..195
    int ntile = sid & 3;                             // 0..3

    int tid  = threadIdx.x;
    int lane = tid & 63, wid = tid >> 6;
    int wm = wid >> 1, wn = wid & 1;                 // 2x2 waves of 64x64
    int l15 = lane & 15, lg = lane >> 4;

    // A staging map: unit u = tid (+256): row = u>>2 (+64), c8 = u&3
    int arowi = tid >> 2;                            // 0..63
    int ac8   = tid & 3;
    const float* agA = enc + (size_t)(mtile * 128 + arowi) * ENC_ + ac8 * 8;
    const float* agB = agA + (size_t)64 * ENC_;
    int wa0 = (ac8 * 128 + arowi) * 8;               // LDS half-offset, unit (k8=c8,row)
    int wa1 = wa0 + 64 * 8;

    // B staging: units tid, tid+256 of the (ntile,kt) tile, linear.
    const _Float16* bbase = WeTs + (size_t)ntile * 64 * 4096;

    // frag read half-offsets
    int afo = (lg * 128 + wm * 64 + l15) * 8;
    int bfo = (lg * 128 + wn * 64 + l15) * 8;

    float4 areg[4];
    f16x8  breg[2];

    f32x4 acc[4][4];
#pragma unroll
    for (int mi = 0; mi < 4; ++mi)
#pragma unroll
        for (int ni = 0; ni < 4; ++ni) acc[mi][ni] = (f32x4){0.f, 0.f, 0.f, 0.f};

    auto loadA = [&](int kt) {
        const float* a0 = agA + kt * 32;
        const float* a1 = agB + kt * 32;
        areg[0] = *reinterpret_cast<const float4*>(a0);
        areg[1] = *reinterpret_cast<const float4*>(a0 + 4);
        areg[2] = *reinterpret_cast<const float4*>(a1);
        areg[3] = *reinterpret_cast<const float4*>(a1 + 4);
    };
    auto loadB = [&](int kt) {
        const _Float16* s = bbase + (size_t)kt * 4096;
        breg[0] = *reinterpret_cast<const f16x8*>(s + tid * 8);
        breg[1] = *reinterpret_cast<const f16x8*>(s + (tid + 256) * 8);
    };
    auto writeT = [&](int buf) {
        _Float16* As = smem[buf][0];
        _Float16* Bs = smem[buf][1];
        union { h16x2 h2[4]; f16x8 h8; } cv;
        cv.h2[0] = __builtin_amdgcn_cvt_pkrtz(areg[0].x, areg[0].y);
        cv.h2[1] = __builtin_amdgcn_cvt_pkrtz(areg[0].z, areg[0].w);
        cv.h2[2] = __builtin_amdgcn_cvt_pkrtz(areg[1].x, areg[1].y);
        cv.h2[3] = __builtin_amdgcn_cvt_pkrtz(areg[1].z, areg[1].w);
        *reinterpret_cast<f16x8*>(As + wa0) = cv.h8;
        cv.h2[0] = __builtin_amdgcn_cvt_pkrtz(areg[2].x, areg[2].y);
        cv.h2[1] = __builtin_amdgcn_cvt_pkrtz(areg[2].z, areg[2].w);
        cv.h2[2] = __builtin_amdgcn_cvt_pkrtz(areg[3].x, areg[3].y);
        cv.h2[3] = __builtin_amdgcn_cvt_pkrtz(areg[3].z, areg[3].w);
        *reinterpret_cast<f16x8*>(As + wa1) = cv.h8;
        *reinterpret_cast<f16x8*>(Bs + tid * 8) = breg[0];
        *reinterpret_cast<f16x8*>(Bs + (tid + 256) * 8) = breg[1];
    };

    loadA(0);
    loadB(0);
    writeT(0);
    __syncthreads();

    int cur = 0;
    for (int kt = 0; kt < 64; ++kt) {
        if (kt < 63) { loadA(kt + 1); loadB(kt + 1); }   // issue early (T14)
        const _Float16* As = smem[cur][0];
        const _Float16* Bs = smem[cur][1];
        f16x8 af[4], bf[4];
#pragma unroll
        for (int mi = 0; mi < 4; ++mi)
            af[mi] = *reinterpret_cast<const f16x8*>(As + afo + mi * 128);
#pragma unroll
        for (int ni = 0; ni < 4; ++ni)
            bf[ni] = *reinterpret_cast<const f16x8*>(Bs + bfo + ni * 128);
#pragma unroll
        for (int mi = 0; mi < 4; ++mi)
#pragma unroll
            for (int ni = 0; ni < 4; ++ni)
                acc[mi][ni] = __builtin_amdgcn_mfma_f32_16x16x32_f16(
                    af[mi], bf[ni], acc[mi][ni], 0, 0, 0);
        if (kt < 63) writeT(cur ^ 1);                    // write-late
        __syncthreads();
        cur ^= 1;
    }

    // Epilogue: x = acc + be[n] + dec[b][n]; t = tanh(x); rowsum += t*wa[n]
    float rsum[4][4];
#pragma unroll
    for (int mi = 0; mi < 4; ++mi)
#pragma unroll
        for (int j = 0; j < 4; ++j) rsum[mi][j] = 0.f;

    int nb = ntile * 128 + wn * 64;
    int rb = mtile * 128 + wm * 64;
#pragma unroll
    for (int ni = 0; ni < 4; ++ni) {
        int n = nb + ni * 16 + l15;
        float wav = wa[n];
        float bev = be[n];
#pragma unroll
        for (int mi = 0; mi < 4; ++mi) {
#pragma unroll
            for (int j = 0; j < 4; ++j) {
                int row = rb + mi * 16 + lg * 4 + j;    // C/D: col=lane&15, row=(lane>>4)*4+reg
                int b = row / L_;
                float x = acc[mi][ni][j] + bev + dec[b * ATT_ + n];
                float e = __expf(2.0f * x);
                float t = 1.0f - 2.0f / (e + 1.0f);     // tanh(x), inf-safe
                rsum[mi][j] += t * wav;
            }
        }
    }
#pragma unroll
    for (int mi = 0; mi < 4; ++mi) {
#pragma unroll
        for (int j = 0; j < 4; ++j) {
            float v = rsum[mi][j];
            v += __shfl_xor(v, 1);
            v += __shfl_xor(v, 2);
            v += __shfl_xor(v, 4);
            v += __shfl_xor(v, 8);
            if (l15 == 0) red[wn][wm * 64 + mi * 16 + lg * 4 + j] = v;
        }
    }
    __syncthreads();
    if (tid < 128)
        partial[(size_t)ntile * M_ + mtile * 128 + tid] = red[0][tid] + red[1][tid];
}

// softmax over L per batch row. ba cancels in softmax -> skipped.
__global__ void softmax_kernel(const float* __restrict__ partial, float* __restrict__ alphas) {
    int b = blockIdx.x, t = threadIdx.x;     // 128 blocks x 256 threads
    int lane = t & 63, wid = t >> 6;
    __shared__ float red[4];
    float s = 0.f, val = -1e30f;
    if (t < L_) {
        int r = b * L_ + t;
        s = partial[r] + partial[M_ + r] + partial[2 * M_ + r] + partial[3 * M_ + r];
        val = s;
    }
    float m = val;
#pragma unroll
    for (int off = 1; off < 64; off <<= 1) m = fmaxf(m, __shfl_xor(m, off));
    if (lane == 0) red[wid] = m;
    __syncthreads();
    m = fmaxf(fmaxf(red[0], red[1]), fmaxf(red[2], red[3]));
    float e = (t < L_) ? __expf(s - m) : 0.f;
    float sum = e;
#pragma unroll
    for (int off = 1; off < 64; off <<= 1) sum += __shfl_xor(sum, off);
    __syncthreads();
    if (lane == 0) red[wid] = sum;
    __syncthreads();
    sum = red[0] + red[1] + red[2] + red[3];
    if (t < L_) alphas[b * L_ + t] = e / sum;
}

// context[b][e] = sum_l alphas[b][l] * enc[b][l][e]   (memory-bound pass)
__global__ void context_kernel(const float* __restrict__ enc, const float* __restrict__ alphas,
                               float* __restrict__ ctx) {
    int b = blockIdx.x >> 2;                  // 128 b x 4 e-chunks = 512 blocks
    int ec = blockIdx.x & 3;
    int e = ec * 512 + threadIdx.x * 2;
    const float* ep = enc + (size_t)b * L_ * ENC_ + e;
    const float* ap = alphas + b * L_;
    float ax = 0.f, ay = 0.f;
#pragma unroll 4
    for (int l = 0; l < L_; ++l) {
        float a = ap[l];
        float2 v = *reinterpret_cast<const float2*>(ep + (size_t)l * ENC_);
        ax += a * v.x;
        ay += a * v.y;
    }
    float2 r; r.x = ax; r.y = ay;
    *reinterpret_cast<float2*>(&ctx[b * ENC_ + e]) = r;
}

extern "C" void kernel_launch(void* const* d_in, const int* in_sizes, int n_in,
                              void* d_out, int out_size, void* d_ws, size_t ws_size,
                              hipStream_t stream) {
    const float* enc = (const float*)d_in[0];
    const float* dh  = (const float*)d_in[1];
    const float* We  = (const float*)d_in[2];
    const float* be  = (const float*)d_in[3];
    const float* Wd  = (const float*)d_in[4];
    const float* bd  = (const float*)d_in[5];
    const float* wa  = (const float*)d_in[6];
    // d_in[7] = ba: shifts all scores equally -> cancels in softmax, unused.

    float* out    = (float*)d_out;
    float* ctx    = out;               // [128][2048]
    float* alphas = out + B_ * ENC_;   // [128][196]

    char* ws = (char*)d_ws;
    float*    dec     = (float*)ws;                            // 256 KiB
    _Float16* WeTs    = (_Float16*)(ws + 262144);              // 2 MiB
    float*    partial = (float*)(ws + 262144 + 2097152);       // 392 KiB

    hipLaunchKernelGGL(wets_kernel,       dim3(512),  dim3(256), 0, stream, We, WeTs);
    hipLaunchKernelGGL(decmap_kernel,     dim3(128),  dim3(512), 0, stream, dh, Wd, bd, dec);
    hipLaunchKernelGGL(gemm_score_kernel, dim3(784),  dim3(256), 0, stream, enc, WeTs, be, wa, dec, partial);
    hipLaunchKernelGGL(softmax_kernel,    dim3(128),  dim3(256), 0, stream, partial, alphas);
    hipLaunchKernelGGL(context_kernel,    dim3(512),  dim3(256), 0, stream, enc, alphas, ctx);
}